// Round 1
// baseline (214.361 us; speedup 1.0000x reference)
//
#include <hip/hip_runtime.h>

// Problem constants (match reference setup_inputs)
#define BB   32
#define CC   64
#define HH   80
#define WW   200
#define NPR  192
#define SS   36

typedef float f32x4 __attribute__((ext_vector_type(4)));
typedef unsigned short u16x8 __attribute__((ext_vector_type(8)));

// fp32 -> bf16 round-to-nearest-even
__device__ __forceinline__ unsigned short f2bf(float f) {
    union { float f; unsigned int u; } v; v.f = f;
    unsigned int u = v.u;
    u += 0x7FFFu + ((u >> 16) & 1u);
    return (unsigned short)(u >> 16);
}
__device__ __forceinline__ float bf2f(unsigned short h) {
    union { unsigned int u; float f; } v; v.u = ((unsigned int)h) << 16;
    return v.f;
}

// y0/y1/wy0/wy1 as a function of s only, replicating the reference fp32 op
// sequence:
//   k = sample_x_indexs[35-s] = floor((35-s)*71/35)   (exact in int arith)
//   pf = 1 - k/71 ; gy = pf*2-1 ; iy = ((gy+1)*0.5)*79
__device__ __forceinline__ void y_of_s(int s, int& y0, int& y1, float& wy0, float& wy1) {
    int k = ((35 - s) * 71) / 35;
    float pf = 1.0f - (float)k / 71.0f;
    float gy = pf * 2.0f - 1.0f;
    float iy = ((gy + 1.0f) * 0.5f) * 79.0f;
    float y0f = floorf(iy);
    y0 = (int)y0f;
    wy1 = iy - y0f;     // == 0 exactly when iy == 79, so clamped y1 is safe
    wy0 = 1.0f - wy1;
    y1 = y0 + 1;
    if (y1 > HH - 1) y1 = HH - 1;
    if (y0 < 0) y0 = 0;
}

// One block per (b, c-PAIR): 1024 blocks x 512 threads = 4 blocks/CU
// (32 waves/CU, one fully resident round). vs the c-quad version this
// quadruples the number of independent barrier domains per CU and halves
// the straggler scope of each __syncthreads(), at identical total traffic.
// comb is bf16 [s][x][c2] (28.8 KB): one 4-B LDS word holds both channels
// at one (s,x); per-n store runs are 288 B contiguous.
__global__ __launch_bounds__(512, 8)
void pool_prior_kernel(const float* __restrict__ feat,
                       const float* __restrict__ prior_xs,
                       float* __restrict__ out) {
    __shared__ unsigned short comb[SS * WW * 2];   // [s][x][c2] bf16, 28.8 KB

    const int blk = blockIdx.x;
    const int b  = blk >> 5;              // / 32
    const int c0 = (blk & 31) * 2;        // channel pair base
    const int tid = threadIdx.x;

    const float* prior_b = prior_xs + (size_t)b * (NPR * SS);

    // ---- Prefetch first half of priors (no LDS dependency -> overlaps staging)
    f32x4 px0 = *(const f32x4*)(prior_b + tid * 4);
    f32x4 px1 = *(const f32x4*)(prior_b + (tid + 512) * 4);

    // ---- Stage y-combined rows, 2 channels, bf16 ----
    // 36 s x 50 float4 = 1800 slots over 512 threads (3 full rounds + 264).
    const float* fc0 = feat + (size_t)(b * CC + c0) * (HH * WW);
    const float* fc1 = fc0 + (HH * WW);
    #pragma unroll
    for (int t = 0; t < 4; ++t) {
        int idx = tid + t * 512;
        if (t < 3 || idx < 1800) {
            int s = idx / 50;              // magic-mul
            int x = (idx - s * 50) * 4;
            int y0, y1; float wy0, wy1;
            y_of_s(s, y0, y1, wy0, wy1);
            f32x4 a0 = *(const f32x4*)(fc0 + y0 * WW + x);
            f32x4 a1 = *(const f32x4*)(fc0 + y1 * WW + x);
            f32x4 b0 = *(const f32x4*)(fc1 + y0 * WW + x);
            f32x4 b1 = *(const f32x4*)(fc1 + y1 * WW + x);
            f32x4 va = wy0 * a0 + wy1 * a1;
            f32x4 vb = wy0 * b0 + wy1 * b1;
            // pack [x+i][c2] bf16; dst is 16B-aligned, one u16x8 store
            u16x8 w = { f2bf(va.x), f2bf(vb.x), f2bf(va.y), f2bf(vb.y),
                        f2bf(va.z), f2bf(vb.z), f2bf(va.w), f2bf(vb.w) };
            *(u16x8*)&comb[(s * WW + x) * 2] = w;
        }
    }
    __syncthreads();

    // ---- Load remaining priors (latency hidden under first process calls)
    f32x4 px2 = *(const f32x4*)(prior_b + (tid + 1024) * 4);
    f32x4 px3 = {0.f, 0.f, 0.f, 0.f};
    if (tid < 192) px3 = *(const f32x4*)(prior_b + (tid + 1536) * 4);

    float* out_bc = out + (size_t)b * ((size_t)NPR * CC * SS) + (size_t)c0 * SS;
    const unsigned int* comb2 = (const unsigned int*)comb;   // 4 B per (s,x)

    // ---- Gather: quad q covers e = 4q..4q+3 (one n), 2 channels ----
    auto process = [&](int q, f32x4 px4) {
        int n = q / 9;                     // e/36 with e=4q
        int s4 = (q - n * 9) * 4;
        float px[4] = {px4.x, px4.y, px4.z, px4.w};
        float rc0[4], rc1[4];
        #pragma unroll
        for (int j = 0; j < 4; ++j) {
            int s = s4 + j;
            float gx = px[j] * 2.0f - 1.0f;
            float ix = ((gx + 1.0f) * 0.5f) * (float)(WW - 1);
            float x0f = floorf(ix);
            int xi = (int)x0f;
            if (xi < 0) xi = 0;
            if (xi > WW - 2) xi = WW - 2;  // unreachable for px in [0,1)
            float wx1 = ix - x0f;
            float wx0 = 1.0f - wx1;
            unsigned int lo = comb2[s * WW + xi];       // both channels at x0
            unsigned int hi = comb2[s * WW + xi + 1];   // both channels at x1
            rc0[j] = wx0 * bf2f((unsigned short)(lo & 0xffffu))
                   + wx1 * bf2f((unsigned short)(hi & 0xffffu));
            rc1[j] = wx0 * bf2f((unsigned short)(lo >> 16))
                   + wx1 * bf2f((unsigned short)(hi >> 16));
        }
        float* o = out_bc + (size_t)n * (CC * SS) + s4;
        f32x4 v0 = { rc0[0], rc0[1], rc0[2], rc0[3] };
        f32x4 v1 = { rc1[0], rc1[1], rc1[2], rc1[3] };
        __builtin_nontemporal_store(v0, (f32x4*)o);
        __builtin_nontemporal_store(v1, (f32x4*)(o + SS));
    };

    process(tid, px0);
    process(tid + 512, px1);
    process(tid + 1024, px2);
    if (tid < 192) process(tid + 1536, px3);   // 1728 quads total
}

extern "C" void kernel_launch(void* const* d_in, const int* in_sizes, int n_in,
                              void* d_out, int out_size, void* d_ws, size_t ws_size,
                              hipStream_t stream) {
    const float* feat  = (const float*)d_in[0];   // (32,64,80,200) fp32
    const float* prior = (const float*)d_in[1];   // (32,192,36)    fp32
    float* out = (float*)d_out;                   // (6144,64,36,1) fp32
    pool_prior_kernel<<<dim3(BB * (CC / 2)), dim3(512), 0, stream>>>(feat, prior, out);
}